// Round 7
// baseline (256.014 us; speedup 1.0000x reference)
//
#include <hip/hip_runtime.h>

#define NV 2708
#define INC 1433
#define PSTR 2720          // padded row len (mult of 32)
#define BSTR 2752          // padded row len for QT16/G2T16 (mult of 64)
#define SLAB ((size_t)(2720*64))   // fp32 partial slab (rows padded to 2720)
#define MWPR 88            // bitmask u32 words per row (43*2=86, pad 88)

typedef __attribute__((ext_vector_type(8))) short bf16x8;
typedef __attribute__((ext_vector_type(4))) float f32x4;
typedef __attribute__((ext_vector_type(4))) unsigned short u16x4;

__device__ __forceinline__ unsigned short f2bf(float f){
  union { float f; unsigned int i; } v; v.f = f;
  return (unsigned short)((v.i + 0x7fffu + ((v.i >> 16) & 1u)) >> 16);  // RNE
}

// =============== pack_mask: A int32 -> bitmask (32x compression) ============
__global__ __launch_bounds__(256) void pack_mask(
    const int* __restrict__ A, unsigned int* __restrict__ Abits)
{
  const int i = blockIdx.x;
  const int lane = threadIdx.x & 63, wave = threadIdx.x >> 6;
  const int* arow = A + (size_t)i*NV;
  if (threadIdx.x < 2) Abits[(size_t)i*MWPR + 86 + threadIdx.x] = 0u;  // pad words
  for (int g = wave; g < 43; g += 4){
    int j = g*64 + lane;
    int a = (j < NV) ? arow[j] : 0;
    unsigned long long m = __ballot(a != 0);
    if (lane == 0){
      Abits[(size_t)i*MWPR + 2*g]     = (unsigned int)m;
      Abits[(size_t)i*MWPR + 2*g + 1] = (unsigned int)(m >> 32);
    }
  }
}

// =============== proj: partials of {K,Q,V} = X @ W^T, split-K ===============
// grid (43, 4, 3). Wave-contiguous staging (lane = k-col).
__global__ __launch_bounds__(256) void proj(
    const float* __restrict__ X, const float* __restrict__ W0,
    const float* __restrict__ W1, const float* __restrict__ W2,
    float* __restrict__ part)
{
  __shared__ __align__(16) unsigned short At[64*72];
  __shared__ __align__(16) unsigned short Bt[64*72];
  const int tid = threadIdx.x;
  const int lane = tid & 63, wave = tid >> 6, quad = lane >> 4, lr = lane & 15;
  const int m0 = blockIdx.x * 64;
  const int s  = blockIdx.y, z = blockIdx.z;
  const float* W = (z==0) ? W0 : (z==1) ? W1 : W2;
  const int kbeg = s * 360, kend = min(kbeg + 360, INC);
  const int wm = (wave & 1) * 32, wn = (wave >> 1) * 32;
  f32x4 acc[2][2] = {};

  for (int k0 = kbeg; k0 < kend; k0 += 64){
    const int kk = k0 + lane;
    const bool kok = kk < kend;
    #pragma unroll
    for (int e = 0; e < 16; e++){
      int row = e*4 + wave;
      float xv = 0.f, wv = 0.f;
      if (kok && (m0 + row) < NV) xv = X[(size_t)(m0+row)*INC + kk];
      if (kok)                    wv = W[(size_t)row*INC + kk];
      At[row*72 + lane] = f2bf(xv);
      Bt[row*72 + lane] = f2bf(wv);
    }
    __syncthreads();
    #pragma unroll
    for (int ks = 0; ks < 2; ks++){
      bf16x8 af[2], bv[2];
      #pragma unroll
      for (int t = 0; t < 2; t++){
        af[t] = *(const bf16x8*)&At[(wm + t*16 + lr)*72 + ks*32 + quad*8];
        bv[t] = *(const bf16x8*)&Bt[(wn + t*16 + lr)*72 + ks*32 + quad*8];
      }
      #pragma unroll
      for (int tm = 0; tm < 2; tm++)
        #pragma unroll
        for (int tn = 0; tn < 2; tn++)
          acc[tm][tn] = __builtin_amdgcn_mfma_f32_16x16x32_bf16(af[tm], bv[tn], acc[tm][tn], 0, 0, 0);
    }
    __syncthreads();
  }
  float* dst = part + (size_t)(z*4 + s) * SLAB;
  #pragma unroll
  for (int tm = 0; tm < 2; tm++)
    #pragma unroll
    for (int tn = 0; tn < 2; tn++)
      #pragma unroll
      for (int e = 0; e < 4; e++){
        int row = m0 + wm + tm*16 + quad*4 + e;
        if (row < NV)
          dst[(size_t)row*64 + wn + tn*16 + lr] = acc[tm][tn][e];
      }
}

// K16f fragment-linear ; QT16 [c][m] ; VTf fragment-linear. grid (688, 3).
__global__ __launch_bounds__(256) void reduce_proj(
    const float* __restrict__ part, unsigned short* __restrict__ K16f,
    unsigned short* __restrict__ QT16, unsigned short* __restrict__ VTf)
{
  int idx = blockIdx.x*256 + threadIdx.x;       // < 2752*64
  int z = blockIdx.y;
  int m = idx >> 6, c = idx & 63;
  float v = 0.f;
  if (m < 2720){
    const float* base = part + (size_t)z*4*SLAB + (size_t)m*64 + c;
    #pragma unroll
    for (int s = 0; s < 4; s++) v += base[s*SLAB];
  }
  unsigned short h = (m < NV) ? f2bf(v) : (unsigned short)0;
  if (z == 0){       // K16f: B-frag linear: ((m>>4)*2+(c>>5))*512 + (m&15)*32 + (c&31)
    if (m < 2720) K16f[((m>>4)*2 + (c>>5))*512 + (m&15)*32 + (c&31)] = h;
  } else if (z == 1){
    QT16[(size_t)c*BSTR + m] = h;
  } else {           // VTf: (m>>5)*2048 + c*32 + (m&31)
    if (m < 2720) VTf[(m>>5)*2048 + c*32 + (m&31)] = h;
  }
}

// =============== gemmG: partials of G = U^T @ Q. grid (43, 13) ==============
__global__ __launch_bounds__(256) void gemmG(
    const float* __restrict__ U, const unsigned short* __restrict__ QT,
    float* __restrict__ part)
{
  __shared__ __align__(16) unsigned short At[64*72];
  __shared__ __align__(16) unsigned short Bt[64*72];
  const int tid = threadIdx.x;
  const int lane = tid & 63, wave = tid >> 6, quad = lane >> 4, lr = lane & 15;
  const int m0 = blockIdx.x * 64;
  const int s  = blockIdx.y;
  const int kbeg = s * 224, kend = min(kbeg + 224, NV);
  const int wm = (wave & 1) * 32, wn = (wave >> 1) * 32;
  f32x4 acc[2][2] = {};

  const bool mok = (m0 + lane) < NV;
  const int bc = tid >> 2, bseg = tid & 3;

  for (int k0 = kbeg; k0 < kend; k0 += 64){
    #pragma unroll
    for (int e = 0; e < 16; e++){
      int klocal = e*4 + wave;
      int krow = k0 + klocal;
      float v = 0.f;
      if (krow < kend && mok) v = U[(size_t)krow*NV + m0 + lane];
      At[lane*72 + klocal] = f2bf(v);
    }
    {
      const unsigned short* q = QT + (size_t)bc*BSTR + k0 + bseg*16;
      *(bf16x8*)&Bt[bc*72 + bseg*16]     = *(const bf16x8*)(q);
      *(bf16x8*)&Bt[bc*72 + bseg*16 + 8] = *(const bf16x8*)(q + 8);
    }
    __syncthreads();
    #pragma unroll
    for (int ks = 0; ks < 2; ks++){
      bf16x8 af[2], bv[2];
      #pragma unroll
      for (int t = 0; t < 2; t++){
        af[t] = *(const bf16x8*)&At[(wm + t*16 + lr)*72 + ks*32 + quad*8];
        bv[t] = *(const bf16x8*)&Bt[(wn + t*16 + lr)*72 + ks*32 + quad*8];
      }
      #pragma unroll
      for (int tm = 0; tm < 2; tm++)
        #pragma unroll
        for (int tn = 0; tn < 2; tn++)
          acc[tm][tn] = __builtin_amdgcn_mfma_f32_16x16x32_bf16(af[tm], bv[tn], acc[tm][tn], 0, 0, 0);
    }
    __syncthreads();
  }
  float* dst = part + (size_t)s * SLAB;
  #pragma unroll
  for (int tm = 0; tm < 2; tm++)
    #pragma unroll
    for (int tn = 0; tn < 2; tn++)
      #pragma unroll
      for (int e = 0; e < 4; e++){
        int row = m0 + wm + tm*16 + quad*4 + e;
        if (row < NV)
          dst[(size_t)row*64 + wn + tn*16 + lr] = acc[tm][tn][e];
      }
}

// G2T16[c][m] = bf16(G[m][c] * lmbd[m]/64), zero pads. grid 688.
__global__ __launch_bounds__(256) void reduce_g(
    const float* __restrict__ part, const float* __restrict__ lm,
    unsigned short* __restrict__ G2T)
{
  int idx = blockIdx.x*256 + threadIdx.x;
  int m = idx >> 6, c = idx & 63;
  unsigned short h = 0;
  if (m < NV){
    const float* base = part + (size_t)m*64 + c;
    float v = 0.f;
    #pragma unroll
    for (int s = 0; s < 13; s++) v += base[s*SLAB];
    h = f2bf(v * lm[m] * (1.0f/64.0f));
  }
  G2T[(size_t)c*BSTR + m] = h;
}

// =============== gemmF: partials of F = U @ G2. grid (43, 13) ===============
__global__ __launch_bounds__(256) void gemmF(
    const float* __restrict__ U, const unsigned short* __restrict__ G2T,
    float* __restrict__ part)
{
  __shared__ __align__(16) unsigned short At[64*72];
  __shared__ __align__(16) unsigned short Bt[64*72];
  const int tid = threadIdx.x;
  const int lane = tid & 63, wave = tid >> 6, quad = lane >> 4, lr = lane & 15;
  const int m0 = blockIdx.x * 64;
  const int s  = blockIdx.y;
  const int kbeg = s * 224, kend = min(kbeg + 224, NV);
  const int wm = (wave & 1) * 32, wn = (wave >> 1) * 32;
  f32x4 acc[2][2] = {};

  const int bc = tid >> 2, bseg = tid & 3;

  for (int k0 = kbeg; k0 < kend; k0 += 64){
    #pragma unroll
    for (int e = 0; e < 4; e++){
      int row = e*16 + wave*4 + (lane >> 4);
      int col = k0 + (lane & 15)*4;
      float4 v = make_float4(0.f,0.f,0.f,0.f);
      if ((m0 + row) < NV && col + 4 <= kend)
        v = *(const float4*)(U + (size_t)(m0+row)*NV + col);
      u16x4 h = { f2bf(v.x), f2bf(v.y), f2bf(v.z), f2bf(v.w) };
      *(u16x4*)&At[row*72 + (lane & 15)*4] = h;    // always stored (zeros past kend)
    }
    {
      const unsigned short* g = G2T + (size_t)bc*BSTR + k0 + bseg*16;
      *(bf16x8*)&Bt[bc*72 + bseg*16]     = *(const bf16x8*)(g);
      *(bf16x8*)&Bt[bc*72 + bseg*16 + 8] = *(const bf16x8*)(g + 8);
    }
    __syncthreads();
    #pragma unroll
    for (int ks = 0; ks < 2; ks++){
      bf16x8 af[2], bv[2];
      #pragma unroll
      for (int t = 0; t < 2; t++){
        af[t] = *(const bf16x8*)&At[(wm + t*16 + lr)*72 + ks*32 + quad*8];
        bv[t] = *(const bf16x8*)&Bt[(wn + t*16 + lr)*72 + ks*32 + quad*8];
      }
      #pragma unroll
      for (int tm = 0; tm < 2; tm++)
        #pragma unroll
        for (int tn = 0; tn < 2; tn++)
          acc[tm][tn] = __builtin_amdgcn_mfma_f32_16x16x32_bf16(af[tm], bv[tn], acc[tm][tn], 0, 0, 0);
    }
    __syncthreads();
  }
  float* dst = part + (size_t)s * SLAB;
  #pragma unroll
  for (int tm = 0; tm < 2; tm++)
    #pragma unroll
    for (int tn = 0; tn < 2; tn++)
      #pragma unroll
      for (int e = 0; e < 4; e++){
        int row = m0 + wm + tm*16 + quad*4 + e;
        if (row < NV)
          dst[(size_t)row*64 + wn + tn*16 + lr] = acc[tm][tn][e];
      }
}

// F16[m][c] rows padded to 2720 (pads zero). grid 680.
__global__ __launch_bounds__(256) void reduce_f(
    const float* __restrict__ part, unsigned short* __restrict__ F16)
{
  int idx = blockIdx.x*256 + threadIdx.x;       // < 2720*64
  int m = idx >> 6;
  float v = 0.f;
  if (m < NV){
    const float* base = part + idx;
    #pragma unroll
    for (int s = 0; s < 13; s++) v += base[s*SLAB];
  }
  F16[idx] = (m < NV) ? f2bf(v) : (unsigned short)0;
}

// ====== fused: |F K^T| -> masked exp (bit-mask) + row-sum -> P V ============
// 4 rows/block, 677 blocks. No max-subtraction: logits = |N(0, <=0.125^2)|,
// exp in [1, ~2.3] -- overflow impossible; softmax ratio mathematically equal.
__global__ __launch_bounds__(256) void fused_attn(
    const unsigned short* __restrict__ F16, const unsigned short* __restrict__ K16f,
    const unsigned int* __restrict__ Abits, const unsigned short* __restrict__ VTf,
    float* __restrict__ Hout)
{
  __shared__ __align__(16) unsigned short pbuf[4*PSTR];
  __shared__ unsigned int mrow[4*MWPR];
  __shared__ float swave[4][4];
  __shared__ float rinv[4];
  const int tid  = threadIdx.x;
  const int lane = tid & 63, wave = tid >> 6;
  const int quad = lane >> 4, lr = lane & 15;
  const int i0 = blockIdx.x * 4;                 // 677*4 = 2708 exactly

  for (int idx = tid; idx < 4*MWPR; idx += 256)
    mrow[idx] = Abits[(size_t)i0*MWPR + idx];
  __syncthreads();

  // ---- phase A: S = F[4 rows] @ K^T, fused mask+exp+partial-sum ----
  const unsigned short* frow = F16 + (size_t)(i0 + (lr & 3))*64;
  bf16x8 af0 = *(const bf16x8*)(frow + quad*8);
  bf16x8 af1 = *(const bf16x8*)(frow + 32 + quad*8);
  float psum[4] = {0.f, 0.f, 0.f, 0.f};
  for (int t = wave; t < 170; t += 4){
    const unsigned short* kb = K16f + t*1024 + lane*16/2 + 0;  // lr*32+quad*8 shorts
    kb = K16f + t*1024 + lr*32 + quad*8;
    bf16x8 b0 = *(const bf16x8*)(kb);
    bf16x8 b1 = *(const bf16x8*)(kb + 512);
    f32x4 sv = {};
    sv = __builtin_amdgcn_mfma_f32_16x16x32_bf16(af0, b0, sv, 0, 0, 0);
    sv = __builtin_amdgcn_mfma_f32_16x16x32_bf16(af1, b1, sv, 0, 0, 0);
    if (quad == 0){                              // D rows 0..3 live in quad 0
      int col = t*16 + lr;
      int wsh = col >> 5, bit = col & 31;
      #pragma unroll
      for (int r = 0; r < 4; r++){
        float p = 0.f;
        if ((mrow[r*MWPR + wsh] >> bit) & 1u) p = __expf(fabsf(sv[r]));
        psum[r] += p;
        pbuf[r*PSTR + col] = f2bf(p);
      }
    }
  }
  #pragma unroll
  for (int r = 0; r < 4; r++){
    float v = psum[r];
    #pragma unroll
    for (int o = 32; o; o >>= 1) v += __shfl_xor(v, o, 64);
    if (lane == 0) swave[wave][r] = v;
  }
  __syncthreads();
  if (tid < 4){
    float sum = swave[0][tid] + swave[1][tid] + swave[2][tid] + swave[3][tid];
    rinv[tid] = (sum > 0.f) ? (1.f/sum) : 0.f;
  }
  __syncthreads();

  // ---- phase C: H = (P V) * rinv ----
  const int c0 = wave * 16;
  const int mr = lr & 3;
  f32x4 acc = {};
  for (int kt = 0; kt < 85; kt++){
    bf16x8 af = *(const bf16x8*)&pbuf[mr*PSTR + kt*32 + quad*8];
    bf16x8 bv = *(const bf16x8*)&VTf[kt*2048 + (c0 + lr)*32 + quad*8];
    acc = __builtin_amdgcn_mfma_f32_16x16x32_bf16(af, bv, acc, 0, 0, 0);
  }
  if (quad == 0){
    #pragma unroll
    for (int e = 0; e < 4; e++)
      Hout[(size_t)(i0+e)*64 + c0 + lr] = acc[e] * rinv[e];
  }
}

extern "C" void kernel_launch(void* const* d_in, const int* in_sizes, int n_in,
                              void* d_out, int out_size, void* d_ws, size_t ws_size,
                              hipStream_t stream){
  (void)in_sizes; (void)n_in; (void)out_size; (void)ws_size;
  const float* X  = (const float*)d_in[0];
  const int*   A  = (const int*)d_in[1];
  const float* U  = (const float*)d_in[2];
  const float* WK = (const float*)d_in[3];
  const float* WQ = (const float*)d_in[4];
  const float* WV = (const float*)d_in[5];
  const float* lm = (const float*)d_in[6];

  char* ws = (char*)d_ws;
  size_t off = 0;
  auto alloc = [&](size_t bytes){ size_t o = off; off = (off + bytes + 255) & ~(size_t)255; return o; };
  float*          part = (float*)(ws + alloc(13*SLAB*4));                   // 9.05 MB
  unsigned short* K16f = (unsigned short*)(ws + alloc((size_t)170*1024*2)); // frag-linear
  unsigned short* QT16 = (unsigned short*)(ws + alloc((size_t)64*BSTR*2));
  unsigned short* G2T  = (unsigned short*)(ws + alloc((size_t)64*BSTR*2));
  unsigned short* VTf  = (unsigned short*)(ws + alloc((size_t)85*2048*2));  // frag-linear
  unsigned short* F16  = (unsigned short*)(ws + alloc((size_t)2720*64*2));
  unsigned int*   Abits= (unsigned int*)(ws + alloc((size_t)NV*MWPR*4));    // 0.95 MB
  // total ~11.8 MB (< 12.32 MB known-good)

  pack_mask<<<dim3(NV), 256, 0, stream>>>(A, Abits);
  proj<<<dim3(43, 4, 3), 256, 0, stream>>>(X, WK, WQ, WV, part);
  reduce_proj<<<dim3(688, 3), 256, 0, stream>>>(part, K16f, QT16, VTf);
  gemmG<<<dim3(43, 13), 256, 0, stream>>>(U, QT16, part);
  reduce_g<<<dim3(688), 256, 0, stream>>>(part, lm, G2T);
  gemmF<<<dim3(43, 13), 256, 0, stream>>>(U, G2T, part);
  reduce_f<<<dim3(680), 256, 0, stream>>>(part, F16);
  fused_attn<<<dim3(NV/4), 256, 0, stream>>>(F16, K16f, Abits, VTf, (float*)d_out);
}

// Round 8
// 213.280 us; speedup vs baseline: 1.2004x; 1.2004x over previous
//
#include <hip/hip_runtime.h>

#define NV 2708
#define INC 1433
#define XCOLS 1472        // padded X/W cols (23*64)
#define UDIM 2752         // padded U dims (43*64)
#define PSTR 2720
#define BSTR 2752
#define SLAB ((size_t)(2752*64))   // fp32 partial slab
#define MWPR 88

typedef __attribute__((ext_vector_type(8))) short bf16x8;
typedef __attribute__((ext_vector_type(4))) float f32x4;
typedef __attribute__((ext_vector_type(4))) unsigned short u16x4;

__device__ __forceinline__ unsigned short f2bf(float f){
  union { float f; unsigned int i; } v; v.f = f;
  return (unsigned short)((v.i + 0x7fffu + ((v.i >> 16) & 1u)) >> 16);  // RNE
}

// ====== convert_pad: fp32 -> bf16 padded copies of U, X, W + A bit-pack =====
// grid (688, 4), one wave per row. All dst fully initialized (pads zero).
__global__ __launch_bounds__(256) void convert_pad(
    const float* __restrict__ X, const float* __restrict__ WK,
    const float* __restrict__ WQ, const float* __restrict__ WV,
    const float* __restrict__ U, const int* __restrict__ A,
    unsigned short* __restrict__ Xbf, unsigned short* __restrict__ Wbf,
    unsigned short* __restrict__ Ubf, unsigned int* __restrict__ Abits)
{
  const int wave = threadIdx.x >> 6, lane = threadIdx.x & 63;
  const int row = blockIdx.x*4 + wave;
  const int y = blockIdx.y;
  if (y == 0){                       // U rows are 16B-aligned: float4 loads
    unsigned short* dst = Ubf + (size_t)row*UDIM;
    if (row < NV){
      const float* src = U + (size_t)row*NV;
      for (int c4 = lane; c4 < UDIM/4; c4 += 64){
        float4 v = make_float4(0.f,0.f,0.f,0.f);
        if (c4 < NV/4) v = *(const float4*)(src + c4*4);   // 677*4 = 2708 exact
        u16x4 h = { f2bf(v.x), f2bf(v.y), f2bf(v.z), f2bf(v.w) };
        *(u16x4*)(dst + c4*4) = h;
      }
    } else {
      u16x4 zz = {0,0,0,0};
      for (int c4 = lane; c4 < UDIM/4; c4 += 64) *(u16x4*)(dst + c4*4) = zz;
    }
  } else if (y == 1){                // X (rows not 16B-aligned: scalar)
    unsigned short* dst = Xbf + (size_t)row*XCOLS;
    if (row < NV){
      const float* src = X + (size_t)row*INC;
      for (int c = lane; c < XCOLS; c += 64)
        dst[c] = (c < INC) ? f2bf(src[c]) : (unsigned short)0;
    } else {
      for (int c = lane; c < XCOLS; c += 64) dst[c] = 0;
    }
  } else if (y == 2){                // W: 3 x 64 rows
    if (row >= 192) return;
    const float* s = (row < 64) ? WK : (row < 128) ? WQ : WV;
    const float* src = s + (size_t)(row & 63)*INC;
    unsigned short* dst = Wbf + (size_t)row*XCOLS;
    for (int c = lane; c < XCOLS; c += 64)
      dst[c] = (c < INC) ? f2bf(src[c]) : (unsigned short)0;
  } else {                           // A -> bitmask
    if (row >= NV) return;
    const int* arow = A + (size_t)row*NV;
    unsigned int* drow = Abits + (size_t)row*MWPR;
    if (lane < 2) drow[86 + lane] = 0u;
    for (int g = 0; g < 43; g++){
      int j = g*64 + lane;
      int a = (j < NV) ? arow[j] : 0;
      unsigned long long m = __ballot(a != 0);
      if (lane == 0){
        drow[2*g]     = (unsigned int)m;
        drow[2*g + 1] = (unsigned int)(m >> 32);
      }
    }
  }
}

// =============== proj: partials of {K,Q,V} = Xbf @ Wbf^T. grid (43,4,3) =====
// Staging: pure b128 copies, guard-free (padded inputs).
__global__ __launch_bounds__(256) void proj(
    const unsigned short* __restrict__ Xbf, const unsigned short* __restrict__ Wbf,
    float* __restrict__ part)
{
  __shared__ __align__(16) unsigned short At[64*72];
  __shared__ __align__(16) unsigned short Bt[64*72];
  const int tid = threadIdx.x;
  const int lane = tid & 63, wave = tid >> 6, quad = lane >> 4, lr = lane & 15;
  const int m0 = blockIdx.x * 64;
  const int s  = blockIdx.y, z = blockIdx.z;
  const int kbeg = s * 384, kend = min(kbeg + 384, XCOLS);
  const int wm = (wave & 1) * 32, wn = (wave >> 1) * 32;
  const unsigned short* Wz = Wbf + (size_t)z*64*XCOLS;
  const int srow = wave*8 + (lane >> 3), seg = lane & 7;
  f32x4 acc[2][2] = {};

  for (int k0 = kbeg; k0 < kend; k0 += 64){
    #pragma unroll
    for (int e = 0; e < 2; e++){
      int row = e*32 + srow;
      bf16x8 xa = *(const bf16x8*)(Xbf + (size_t)(m0+row)*XCOLS + k0 + seg*8);
      bf16x8 wb = *(const bf16x8*)(Wz  + (size_t)row*XCOLS      + k0 + seg*8);
      *(bf16x8*)&At[row*72 + seg*8] = xa;
      *(bf16x8*)&Bt[row*72 + seg*8] = wb;
    }
    __syncthreads();
    #pragma unroll
    for (int ks = 0; ks < 2; ks++){
      bf16x8 af[2], bv[2];
      #pragma unroll
      for (int t = 0; t < 2; t++){
        af[t] = *(const bf16x8*)&At[(wm + t*16 + lr)*72 + ks*32 + quad*8];
        bv[t] = *(const bf16x8*)&Bt[(wn + t*16 + lr)*72 + ks*32 + quad*8];
      }
      #pragma unroll
      for (int tm = 0; tm < 2; tm++)
        #pragma unroll
        for (int tn = 0; tn < 2; tn++)
          acc[tm][tn] = __builtin_amdgcn_mfma_f32_16x16x32_bf16(af[tm], bv[tn], acc[tm][tn], 0, 0, 0);
    }
    __syncthreads();
  }
  float* dst = part + (size_t)(z*4 + s) * SLAB;
  #pragma unroll
  for (int tm = 0; tm < 2; tm++)
    #pragma unroll
    for (int tn = 0; tn < 2; tn++)
      #pragma unroll
      for (int e = 0; e < 4; e++)
        dst[(size_t)(m0 + wm + tm*16 + quad*4 + e)*64 + wn + tn*16 + lr] = acc[tm][tn][e];
}

// K16f frag-linear ; QT16 [c][m] ; VTf frag-linear. grid (688, 3).
__global__ __launch_bounds__(256) void reduce_proj(
    const float* __restrict__ part, unsigned short* __restrict__ K16f,
    unsigned short* __restrict__ QT16, unsigned short* __restrict__ VTf)
{
  int idx = blockIdx.x*256 + threadIdx.x;       // < 2752*64
  int z = blockIdx.y;
  int m = idx >> 6, c = idx & 63;
  const float* base = part + (size_t)z*4*SLAB + idx;
  float v = 0.f;
  #pragma unroll
  for (int s = 0; s < 4; s++) v += base[s*SLAB];
  unsigned short h = (m < NV) ? f2bf(v) : (unsigned short)0;
  if (z == 0){
    if (m < 2720) K16f[((m>>4)*2 + (c>>5))*512 + (m&15)*32 + (c&31)] = h;
  } else if (z == 1){
    QT16[(size_t)c*BSTR + m] = h;
  } else {
    if (m < 2720) VTf[(m>>5)*2048 + c*32 + (m&31)] = h;
  }
}

// =============== gemmG: partials of G = Ubf^T @ Q. grid (43,15) =============
__global__ __launch_bounds__(256) void gemmG(
    const unsigned short* __restrict__ Ubf, const unsigned short* __restrict__ QT,
    float* __restrict__ part)
{
  __shared__ __align__(16) unsigned short At[64*72];
  __shared__ __align__(16) unsigned short Bt[64*72];
  const int tid = threadIdx.x;
  const int lane = tid & 63, wave = tid >> 6, quad = lane >> 4, lr = lane & 15;
  const int m0 = blockIdx.x * 64;
  const int s  = blockIdx.y;
  const int kbeg = s * 192, kend = min(kbeg + 192, UDIM);
  const int wm = (wave & 1) * 32, wn = (wave >> 1) * 32;
  const int bc = tid >> 2, bseg = tid & 3;
  const int ml = (lane & 15)*4, koff = wave*16 + (lane >> 4);
  f32x4 acc[2][2] = {};

  for (int k0 = kbeg; k0 < kend; k0 += 64){
    #pragma unroll
    for (int e = 0; e < 4; e++){
      int kl = koff + e*4;
      u16x4 v = *(const u16x4*)(Ubf + (size_t)(k0+kl)*UDIM + m0 + ml);
      At[(ml+0)*72 + kl] = v[0];
      At[(ml+1)*72 + kl] = v[1];
      At[(ml+2)*72 + kl] = v[2];
      At[(ml+3)*72 + kl] = v[3];
    }
    {
      const unsigned short* q = QT + (size_t)bc*BSTR + k0 + bseg*16;
      *(bf16x8*)&Bt[bc*72 + bseg*16]     = *(const bf16x8*)(q);
      *(bf16x8*)&Bt[bc*72 + bseg*16 + 8] = *(const bf16x8*)(q + 8);
    }
    __syncthreads();
    #pragma unroll
    for (int ks = 0; ks < 2; ks++){
      bf16x8 af[2], bv[2];
      #pragma unroll
      for (int t = 0; t < 2; t++){
        af[t] = *(const bf16x8*)&At[(wm + t*16 + lr)*72 + ks*32 + quad*8];
        bv[t] = *(const bf16x8*)&Bt[(wn + t*16 + lr)*72 + ks*32 + quad*8];
      }
      #pragma unroll
      for (int tm = 0; tm < 2; tm++)
        #pragma unroll
        for (int tn = 0; tn < 2; tn++)
          acc[tm][tn] = __builtin_amdgcn_mfma_f32_16x16x32_bf16(af[tm], bv[tn], acc[tm][tn], 0, 0, 0);
    }
    __syncthreads();
  }
  float* dst = part + (size_t)s * SLAB;
  #pragma unroll
  for (int tm = 0; tm < 2; tm++)
    #pragma unroll
    for (int tn = 0; tn < 2; tn++)
      #pragma unroll
      for (int e = 0; e < 4; e++)
        dst[(size_t)(m0 + wm + tm*16 + quad*4 + e)*64 + wn + tn*16 + lr] = acc[tm][tn][e];
}

// G2T16[c][m] = bf16(G[m][c] * lmbd[m]/64), zero pads. grid 688.
__global__ __launch_bounds__(256) void reduce_g(
    const float* __restrict__ part, const float* __restrict__ lm,
    unsigned short* __restrict__ G2T)
{
  int idx = blockIdx.x*256 + threadIdx.x;
  int m = idx >> 6, c = idx & 63;
  const float* base = part + idx;
  float v = 0.f;
  #pragma unroll
  for (int s = 0; s < 15; s++) v += base[s*SLAB];
  unsigned short h = 0;
  if (m < NV) h = f2bf(v * lm[m] * (1.0f/64.0f));
  G2T[(size_t)c*BSTR + m] = h;
}

// =============== gemmF: partials of F = Ubf @ G2. grid (43,15) ==============
__global__ __launch_bounds__(256) void gemmF(
    const unsigned short* __restrict__ Ubf, const unsigned short* __restrict__ G2T,
    float* __restrict__ part)
{
  __shared__ __align__(16) unsigned short At[64*72];
  __shared__ __align__(16) unsigned short Bt[64*72];
  const int tid = threadIdx.x;
  const int lane = tid & 63, wave = tid >> 6, quad = lane >> 4, lr = lane & 15;
  const int m0 = blockIdx.x * 64;
  const int s  = blockIdx.y;
  const int kbeg = s * 192, kend = min(kbeg + 192, UDIM);
  const int wm = (wave & 1) * 32, wn = (wave >> 1) * 32;
  const int bc = tid >> 2, bseg = tid & 3;
  const int srow = wave*8 + (lane >> 3), seg = lane & 7;
  f32x4 acc[2][2] = {};

  for (int k0 = kbeg; k0 < kend; k0 += 64){
    #pragma unroll
    for (int e = 0; e < 2; e++){
      int row = e*32 + srow;
      bf16x8 ua = *(const bf16x8*)(Ubf + (size_t)(m0+row)*UDIM + k0 + seg*8);
      *(bf16x8*)&At[row*72 + seg*8] = ua;
    }
    {
      const unsigned short* g = G2T + (size_t)bc*BSTR + k0 + bseg*16;
      *(bf16x8*)&Bt[bc*72 + bseg*16]     = *(const bf16x8*)(g);
      *(bf16x8*)&Bt[bc*72 + bseg*16 + 8] = *(const bf16x8*)(g + 8);
    }
    __syncthreads();
    #pragma unroll
    for (int ks = 0; ks < 2; ks++){
      bf16x8 af[2], bv[2];
      #pragma unroll
      for (int t = 0; t < 2; t++){
        af[t] = *(const bf16x8*)&At[(wm + t*16 + lr)*72 + ks*32 + quad*8];
        bv[t] = *(const bf16x8*)&Bt[(wn + t*16 + lr)*72 + ks*32 + quad*8];
      }
      #pragma unroll
      for (int tm = 0; tm < 2; tm++)
        #pragma unroll
        for (int tn = 0; tn < 2; tn++)
          acc[tm][tn] = __builtin_amdgcn_mfma_f32_16x16x32_bf16(af[tm], bv[tn], acc[tm][tn], 0, 0, 0);
    }
    __syncthreads();
  }
  float* dst = part + (size_t)s * SLAB;
  #pragma unroll
  for (int tm = 0; tm < 2; tm++)
    #pragma unroll
    for (int tn = 0; tn < 2; tn++)
      #pragma unroll
      for (int e = 0; e < 4; e++)
        dst[(size_t)(m0 + wm + tm*16 + quad*4 + e)*64 + wn + tn*16 + lr] = acc[tm][tn][e];
}

// F16[m][c] rows padded to 2720 (pads zero). grid 680.
__global__ __launch_bounds__(256) void reduce_f(
    const float* __restrict__ part, unsigned short* __restrict__ F16)
{
  int idx = blockIdx.x*256 + threadIdx.x;       // < 2720*64
  int m = idx >> 6;
  const float* base = part + idx;
  float v = 0.f;
  #pragma unroll
  for (int s = 0; s < 15; s++) v += base[s*SLAB];
  F16[idx] = (m < NV) ? f2bf(v) : (unsigned short)0;
}

// ====== fused: |F K^T| -> masked exp (bit-mask) + row-sum -> P V ============
// 4 rows/block, 677 blocks. No max-subtraction: logits = |N(0, <=0.125^2)|,
// exp in [1, ~2.3] -- overflow impossible; softmax ratio mathematically equal.
__global__ __launch_bounds__(256) void fused_attn(
    const unsigned short* __restrict__ F16, const unsigned short* __restrict__ K16f,
    const unsigned int* __restrict__ Abits, const unsigned short* __restrict__ VTf,
    float* __restrict__ Hout)
{
  __shared__ __align__(16) unsigned short pbuf[4*PSTR];
  __shared__ unsigned int mrow[4*MWPR];
  __shared__ float swave[4][4];
  __shared__ float rinv[4];
  const int tid  = threadIdx.x;
  const int lane = tid & 63, wave = tid >> 6;
  const int quad = lane >> 4, lr = lane & 15;
  const int i0 = blockIdx.x * 4;

  for (int idx = tid; idx < 4*MWPR; idx += 256)
    mrow[idx] = Abits[(size_t)i0*MWPR + idx];
  __syncthreads();

  const unsigned short* frow = F16 + (size_t)(i0 + (lr & 3))*64;
  bf16x8 af0 = *(const bf16x8*)(frow + quad*8);
  bf16x8 af1 = *(const bf16x8*)(frow + 32 + quad*8);
  float psum[4] = {0.f, 0.f, 0.f, 0.f};
  for (int t = wave; t < 170; t += 4){
    const unsigned short* kb = K16f + t*1024 + lr*32 + quad*8;
    bf16x8 b0 = *(const bf16x8*)(kb);
    bf16x8 b1 = *(const bf16x8*)(kb + 512);
    f32x4 sv = {};
    sv = __builtin_amdgcn_mfma_f32_16x16x32_bf16(af0, b0, sv, 0, 0, 0);
    sv = __builtin_amdgcn_mfma_f32_16x16x32_bf16(af1, b1, sv, 0, 0, 0);
    if (quad == 0){
      int col = t*16 + lr;
      int wsh = col >> 5, bit = col & 31;
      #pragma unroll
      for (int r = 0; r < 4; r++){
        float p = 0.f;
        if ((mrow[r*MWPR + wsh] >> bit) & 1u) p = __expf(fabsf(sv[r]));
        psum[r] += p;
        pbuf[r*PSTR + col] = f2bf(p);
      }
    }
  }
  #pragma unroll
  for (int r = 0; r < 4; r++){
    float v = psum[r];
    #pragma unroll
    for (int o = 32; o; o >>= 1) v += __shfl_xor(v, o, 64);
    if (lane == 0) swave[wave][r] = v;
  }
  __syncthreads();
  if (tid < 4){
    float sum = swave[0][tid] + swave[1][tid] + swave[2][tid] + swave[3][tid];
    rinv[tid] = (sum > 0.f) ? (1.f/sum) : 0.f;
  }
  __syncthreads();

  const int c0 = wave * 16;
  const int mr = lr & 3;
  f32x4 acc = {};
  for (int kt = 0; kt < 85; kt++){
    bf16x8 af = *(const bf16x8*)&pbuf[mr*PSTR + kt*32 + quad*8];
    bf16x8 bv = *(const bf16x8*)&VTf[kt*2048 + (c0 + lr)*32 + quad*8];
    acc = __builtin_amdgcn_mfma_f32_16x16x32_bf16(af, bv, acc, 0, 0, 0);
  }
  if (quad == 0){
    #pragma unroll
    for (int e = 0; e < 4; e++)
      Hout[(size_t)(i0+e)*64 + c0 + lr] = acc[e] * rinv[e];
  }
}

extern "C" void kernel_launch(void* const* d_in, const int* in_sizes, int n_in,
                              void* d_out, int out_size, void* d_ws, size_t ws_size,
                              hipStream_t stream){
  (void)in_sizes; (void)n_in; (void)out_size; (void)ws_size;
  const float* X  = (const float*)d_in[0];
  const int*   A  = (const int*)d_in[1];
  const float* U  = (const float*)d_in[2];
  const float* WK = (const float*)d_in[3];
  const float* WQ = (const float*)d_in[4];
  const float* WV = (const float*)d_in[5];
  const float* lm = (const float*)d_in[6];

  char* ws = (char*)d_ws;
  size_t off = 0;
  auto alloc = [&](size_t bytes){ size_t o = off; off = (off + bytes + 255) & ~(size_t)255; return o; };
  float*          part = (float*)(ws + alloc(15*SLAB*4));                      // 10.57 MB
  unsigned short* Ubf  = (unsigned short*)(ws + alloc((size_t)UDIM*UDIM*2));   // 15.15 MB
  unsigned short* Xbf  = (unsigned short*)(ws + alloc((size_t)UDIM*XCOLS*2));  // 8.10 MB
  unsigned short* Wbf  = (unsigned short*)(ws + alloc((size_t)192*XCOLS*2));   // 0.57 MB
  unsigned short* K16f = (unsigned short*)(ws + alloc((size_t)170*1024*2));
  unsigned short* QT16 = (unsigned short*)(ws + alloc((size_t)64*BSTR*2));
  unsigned short* G2T  = (unsigned short*)(ws + alloc((size_t)64*BSTR*2));
  unsigned short* VTf  = (unsigned short*)(ws + alloc((size_t)85*2048*2));
  unsigned short* F16  = (unsigned short*)(ws + alloc((size_t)2720*64*2));
  unsigned int*   Abits= (unsigned int*)(ws + alloc((size_t)NV*MWPR*4));       // 0.95 MB
  // total ~35.4 MB -- assumes ws_size >= 36 MB

  convert_pad<<<dim3(688, 4), 256, 0, stream>>>(X, WK, WQ, WV, U, A, Xbf, Wbf, Ubf, Abits);
  proj<<<dim3(43, 4, 3), 256, 0, stream>>>(Xbf, Wbf, part);
  reduce_proj<<<dim3(688, 3), 256, 0, stream>>>(part, K16f, QT16, VTf);
  gemmG<<<dim3(43, 15), 256, 0, stream>>>(Ubf, QT16, part);
  reduce_g<<<dim3(688), 256, 0, stream>>>(part, lm, G2T);
  gemmF<<<dim3(43, 15), 256, 0, stream>>>(Ubf, G2T, part);
  reduce_f<<<dim3(680), 256, 0, stream>>>(part, F16);
  fused_attn<<<dim3(NV/4), 256, 0, stream>>>(F16, K16f, Abits, VTf, (float*)d_out);
}

// Round 9
// 197.846 us; speedup vs baseline: 1.2940x; 1.0780x over previous
//
#include <hip/hip_runtime.h>

#define NV 2708
#define INC 1433
#define XCOLS 1472        // padded X/W cols (23*64)
#define UDIM 2752         // padded U dims (43*64)
#define PSTR 2720
#define BSTR 2752
#define SLAB ((size_t)(2752*64))   // fp32 partial slab
#define MWPR 88

typedef __attribute__((ext_vector_type(8))) short bf16x8;
typedef __attribute__((ext_vector_type(4))) float f32x4;
typedef __attribute__((ext_vector_type(4))) unsigned short u16x4;

__device__ __forceinline__ unsigned short f2bf(float f){
  union { float f; unsigned int i; } v; v.f = f;
  return (unsigned short)((v.i + 0x7fffu + ((v.i >> 16) & 1u)) >> 16);  // RNE
}

// ====== convert_all: one-row blocks, short per-wave chains ==================
// blocks: [0,2752) U rows ; [2752,5504) X rows ; [5504,5696) W rows ;
//         [5696,8404) A rows -> bitmask (43 ballot groups split over 4 waves)
__global__ __launch_bounds__(256) void convert_all(
    const float* __restrict__ X, const float* __restrict__ WK,
    const float* __restrict__ WQ, const float* __restrict__ WV,
    const float* __restrict__ U, const int* __restrict__ A,
    unsigned short* __restrict__ Xbf, unsigned short* __restrict__ Wbf,
    unsigned short* __restrict__ Ubf, unsigned int* __restrict__ Abits)
{
  const int bx = blockIdx.x;
  const int tid = threadIdx.x;
  if (bx < 2752){                      // U row (16B-aligned: float4)
    const int row = bx;
    unsigned short* dst = Ubf + (size_t)row*UDIM;
    if (row < NV){
      const float* src = U + (size_t)row*NV;
      for (int c4 = tid; c4 < 688; c4 += 256){
        float4 v = make_float4(0.f,0.f,0.f,0.f);
        if (c4 < 677) v = *(const float4*)(src + c4*4);   // 677*4 = 2708 exact
        u16x4 h = { f2bf(v.x), f2bf(v.y), f2bf(v.z), f2bf(v.w) };
        *(u16x4*)(dst + c4*4) = h;
      }
    } else {
      u16x4 zz = {0,0,0,0};
      for (int c4 = tid; c4 < 688; c4 += 256) *(u16x4*)(dst + c4*4) = zz;
    }
  } else if (bx < 5504){               // X row (4B-aligned: scalar)
    const int row = bx - 2752;
    unsigned short* dst = Xbf + (size_t)row*XCOLS;
    if (row < NV){
      const float* src = X + (size_t)row*INC;
      for (int c = tid; c < XCOLS; c += 256)
        dst[c] = (c < INC) ? f2bf(src[c]) : (unsigned short)0;
    } else {
      for (int c = tid; c < XCOLS; c += 256) dst[c] = 0;
    }
  } else if (bx < 5696){               // W row (192 rows)
    const int row = bx - 5504;
    const float* s = (row < 64) ? WK : (row < 128) ? WQ : WV;
    const float* src = s + (size_t)(row & 63)*INC;
    unsigned short* dst = Wbf + (size_t)row*XCOLS;
    for (int c = tid; c < XCOLS; c += 256)
      dst[c] = (c < INC) ? f2bf(src[c]) : (unsigned short)0;
  } else {                             // A row -> bitmask
    const int i = bx - 5696;
    const int lane = tid & 63, wave = tid >> 6;
    const int* arow = A + (size_t)i*NV;
    unsigned int* drow = Abits + (size_t)i*MWPR;
    if (tid < 2) drow[86 + tid] = 0u;
    for (int g = wave; g < 43; g += 4){    // 11 iters/wave (was 43 serial)
      int j = g*64 + lane;
      int a = (j < NV) ? arow[j] : 0;
      unsigned long long m = __ballot(a != 0);
      if (lane == 0){
        drow[2*g]     = (unsigned int)m;
        drow[2*g + 1] = (unsigned int)(m >> 32);
      }
    }
  }
}

// =============== proj: partials of {K,Q,V} = Xbf @ Wbf^T. grid (43,4,3) =====
__global__ __launch_bounds__(256) void proj(
    const unsigned short* __restrict__ Xbf, const unsigned short* __restrict__ Wbf,
    float* __restrict__ part)
{
  __shared__ __align__(16) unsigned short At[64*72];
  __shared__ __align__(16) unsigned short Bt[64*72];
  const int tid = threadIdx.x;
  const int lane = tid & 63, wave = tid >> 6, quad = lane >> 4, lr = lane & 15;
  const int m0 = blockIdx.x * 64;
  const int s  = blockIdx.y, z = blockIdx.z;
  const int kbeg = s * 384, kend = min(kbeg + 384, XCOLS);
  const int wm = (wave & 1) * 32, wn = (wave >> 1) * 32;
  const unsigned short* Wz = Wbf + (size_t)z*64*XCOLS;
  const int srow = wave*8 + (lane >> 3), seg = lane & 7;
  f32x4 acc[2][2] = {};

  for (int k0 = kbeg; k0 < kend; k0 += 64){
    #pragma unroll
    for (int e = 0; e < 2; e++){
      int row = e*32 + srow;
      bf16x8 xa = *(const bf16x8*)(Xbf + (size_t)(m0+row)*XCOLS + k0 + seg*8);
      bf16x8 wb = *(const bf16x8*)(Wz  + (size_t)row*XCOLS      + k0 + seg*8);
      *(bf16x8*)&At[row*72 + seg*8] = xa;
      *(bf16x8*)&Bt[row*72 + seg*8] = wb;
    }
    __syncthreads();
    #pragma unroll
    for (int ks = 0; ks < 2; ks++){
      bf16x8 af[2], bv[2];
      #pragma unroll
      for (int t = 0; t < 2; t++){
        af[t] = *(const bf16x8*)&At[(wm + t*16 + lr)*72 + ks*32 + quad*8];
        bv[t] = *(const bf16x8*)&Bt[(wn + t*16 + lr)*72 + ks*32 + quad*8];
      }
      #pragma unroll
      for (int tm = 0; tm < 2; tm++)
        #pragma unroll
        for (int tn = 0; tn < 2; tn++)
          acc[tm][tn] = __builtin_amdgcn_mfma_f32_16x16x32_bf16(af[tm], bv[tn], acc[tm][tn], 0, 0, 0);
    }
    __syncthreads();
  }
  float* dst = part + (size_t)(z*4 + s) * SLAB;
  #pragma unroll
  for (int tm = 0; tm < 2; tm++)
    #pragma unroll
    for (int tn = 0; tn < 2; tn++)
      #pragma unroll
      for (int e = 0; e < 4; e++)
        dst[(size_t)(m0 + wm + tm*16 + quad*4 + e)*64 + wn + tn*16 + lr] = acc[tm][tn][e];
}

// K16f frag-linear ; QT16 [c][m] ; VTf frag-linear. grid (688, 3).
__global__ __launch_bounds__(256) void reduce_proj(
    const float* __restrict__ part, unsigned short* __restrict__ K16f,
    unsigned short* __restrict__ QT16, unsigned short* __restrict__ VTf)
{
  int idx = blockIdx.x*256 + threadIdx.x;       // < 2752*64
  int z = blockIdx.y;
  int m = idx >> 6, c = idx & 63;
  const float* base = part + (size_t)z*4*SLAB + idx;
  float v = 0.f;
  #pragma unroll
  for (int s = 0; s < 4; s++) v += base[s*SLAB];
  unsigned short h = (m < NV) ? f2bf(v) : (unsigned short)0;
  if (z == 0){
    if (m < 2720) K16f[((m>>4)*2 + (c>>5))*512 + (m&15)*32 + (c&31)] = h;
  } else if (z == 1){
    QT16[(size_t)c*BSTR + m] = h;
  } else {
    if (m < 2720) VTf[(m>>5)*2048 + c*32 + (m&31)] = h;
  }
}

// =============== gemmG: partials of G = Ubf^T @ Q. grid (43,15) =============
__global__ __launch_bounds__(256) void gemmG(
    const unsigned short* __restrict__ Ubf, const unsigned short* __restrict__ QT,
    float* __restrict__ part)
{
  __shared__ __align__(16) unsigned short At[64*72];
  __shared__ __align__(16) unsigned short Bt[64*72];
  const int tid = threadIdx.x;
  const int lane = tid & 63, wave = tid >> 6, quad = lane >> 4, lr = lane & 15;
  const int m0 = blockIdx.x * 64;
  const int s  = blockIdx.y;
  const int kbeg = s * 192, kend = min(kbeg + 192, UDIM);
  const int wm = (wave & 1) * 32, wn = (wave >> 1) * 32;
  const int bc = tid >> 2, bseg = tid & 3;
  const int ml = (lane & 15)*4, koff = wave*16 + (lane >> 4);
  f32x4 acc[2][2] = {};

  for (int k0 = kbeg; k0 < kend; k0 += 64){
    #pragma unroll
    for (int e = 0; e < 4; e++){
      int kl = koff + e*4;
      u16x4 v = *(const u16x4*)(Ubf + (size_t)(k0+kl)*UDIM + m0 + ml);
      At[(ml+0)*72 + kl] = v[0];
      At[(ml+1)*72 + kl] = v[1];
      At[(ml+2)*72 + kl] = v[2];
      At[(ml+3)*72 + kl] = v[3];
    }
    {
      const unsigned short* q = QT + (size_t)bc*BSTR + k0 + bseg*16;
      *(bf16x8*)&Bt[bc*72 + bseg*16]     = *(const bf16x8*)(q);
      *(bf16x8*)&Bt[bc*72 + bseg*16 + 8] = *(const bf16x8*)(q + 8);
    }
    __syncthreads();
    #pragma unroll
    for (int ks = 0; ks < 2; ks++){
      bf16x8 af[2], bv[2];
      #pragma unroll
      for (int t = 0; t < 2; t++){
        af[t] = *(const bf16x8*)&At[(wm + t*16 + lr)*72 + ks*32 + quad*8];
        bv[t] = *(const bf16x8*)&Bt[(wn + t*16 + lr)*72 + ks*32 + quad*8];
      }
      #pragma unroll
      for (int tm = 0; tm < 2; tm++)
        #pragma unroll
        for (int tn = 0; tn < 2; tn++)
          acc[tm][tn] = __builtin_amdgcn_mfma_f32_16x16x32_bf16(af[tm], bv[tn], acc[tm][tn], 0, 0, 0);
    }
    __syncthreads();
  }
  float* dst = part + (size_t)s * SLAB;
  #pragma unroll
  for (int tm = 0; tm < 2; tm++)
    #pragma unroll
    for (int tn = 0; tn < 2; tn++)
      #pragma unroll
      for (int e = 0; e < 4; e++)
        dst[(size_t)(m0 + wm + tm*16 + quad*4 + e)*64 + wn + tn*16 + lr] = acc[tm][tn][e];
}

// G2T16[c][m] = bf16(G[m][c] * lmbd[m]/64), zero pads. grid 688.
__global__ __launch_bounds__(256) void reduce_g(
    const float* __restrict__ part, const float* __restrict__ lm,
    unsigned short* __restrict__ G2T)
{
  int idx = blockIdx.x*256 + threadIdx.x;
  int m = idx >> 6, c = idx & 63;
  const float* base = part + idx;
  float v = 0.f;
  #pragma unroll
  for (int s = 0; s < 15; s++) v += base[s*SLAB];
  unsigned short h = 0;
  if (m < NV) h = f2bf(v * lm[m] * (1.0f/64.0f));
  G2T[(size_t)c*BSTR + m] = h;
}

// =============== gemmF: partials of F = Ubf @ G2. grid (43,15) ==============
__global__ __launch_bounds__(256) void gemmF(
    const unsigned short* __restrict__ Ubf, const unsigned short* __restrict__ G2T,
    float* __restrict__ part)
{
  __shared__ __align__(16) unsigned short At[64*72];
  __shared__ __align__(16) unsigned short Bt[64*72];
  const int tid = threadIdx.x;
  const int lane = tid & 63, wave = tid >> 6, quad = lane >> 4, lr = lane & 15;
  const int m0 = blockIdx.x * 64;
  const int s  = blockIdx.y;
  const int kbeg = s * 192, kend = min(kbeg + 192, UDIM);
  const int wm = (wave & 1) * 32, wn = (wave >> 1) * 32;
  const int bc = tid >> 2, bseg = tid & 3;
  const int srow = wave*8 + (lane >> 3), seg = lane & 7;
  f32x4 acc[2][2] = {};

  for (int k0 = kbeg; k0 < kend; k0 += 64){
    #pragma unroll
    for (int e = 0; e < 2; e++){
      int row = e*32 + srow;
      bf16x8 ua = *(const bf16x8*)(Ubf + (size_t)(m0+row)*UDIM + k0 + seg*8);
      *(bf16x8*)&At[row*72 + seg*8] = ua;
    }
    {
      const unsigned short* g = G2T + (size_t)bc*BSTR + k0 + bseg*16;
      *(bf16x8*)&Bt[bc*72 + bseg*16]     = *(const bf16x8*)(g);
      *(bf16x8*)&Bt[bc*72 + bseg*16 + 8] = *(const bf16x8*)(g + 8);
    }
    __syncthreads();
    #pragma unroll
    for (int ks = 0; ks < 2; ks++){
      bf16x8 af[2], bv[2];
      #pragma unroll
      for (int t = 0; t < 2; t++){
        af[t] = *(const bf16x8*)&At[(wm + t*16 + lr)*72 + ks*32 + quad*8];
        bv[t] = *(const bf16x8*)&Bt[(wn + t*16 + lr)*72 + ks*32 + quad*8];
      }
      #pragma unroll
      for (int tm = 0; tm < 2; tm++)
        #pragma unroll
        for (int tn = 0; tn < 2; tn++)
          acc[tm][tn] = __builtin_amdgcn_mfma_f32_16x16x32_bf16(af[tm], bv[tn], acc[tm][tn], 0, 0, 0);
    }
    __syncthreads();
  }
  float* dst = part + (size_t)s * SLAB;
  #pragma unroll
  for (int tm = 0; tm < 2; tm++)
    #pragma unroll
    for (int tn = 0; tn < 2; tn++)
      #pragma unroll
      for (int e = 0; e < 4; e++)
        dst[(size_t)(m0 + wm + tm*16 + quad*4 + e)*64 + wn + tn*16 + lr] = acc[tm][tn][e];
}

// F16[m][c] rows padded to 2720 (pads zero). grid 680.
__global__ __launch_bounds__(256) void reduce_f(
    const float* __restrict__ part, unsigned short* __restrict__ F16)
{
  int idx = blockIdx.x*256 + threadIdx.x;       // < 2720*64
  int m = idx >> 6;
  const float* base = part + idx;
  float v = 0.f;
  #pragma unroll
  for (int s = 0; s < 15; s++) v += base[s*SLAB];
  F16[idx] = (m < NV) ? f2bf(v) : (unsigned short)0;
}

// ====== fused: |F K^T| -> masked exp (bit-mask) + row-sum -> P V ============
// 8 rows/block, 339 blocks (halves K16f/VTf L2 traffic vs 4-row).
// quad 0 owns P-rows 0..3, quad 1 rows 4..7; per-quad 16-lane shuffle reduce.
__global__ __launch_bounds__(256) void fused_attn(
    const unsigned short* __restrict__ F16, const unsigned short* __restrict__ K16f,
    const unsigned int* __restrict__ Abits, const unsigned short* __restrict__ VTf,
    float* __restrict__ Hout)
{
  __shared__ __align__(16) unsigned short pbuf[8*PSTR];   // 43.5 KB
  __shared__ unsigned int mrow[8*MWPR];
  __shared__ float swave[4][8];
  __shared__ float rinv[8];
  const int tid  = threadIdx.x;
  const int lane = tid & 63, wave = tid >> 6;
  const int quad = lane >> 4, lr = lane & 15;
  const int i0 = blockIdx.x * 8;

  for (int idx = tid; idx < 8*MWPR; idx += 256){
    int r = idx / MWPR;
    unsigned int v = 0;
    if (i0 + r < NV) v = Abits[(size_t)(i0 + r)*MWPR + (idx - r*MWPR)];
    mrow[idx] = v;
  }
  __syncthreads();

  const unsigned short* frow = F16 + (size_t)(i0 + (lr & 7))*64;  // <2720 padded rows
  bf16x8 af0 = *(const bf16x8*)(frow + quad*8);
  bf16x8 af1 = *(const bf16x8*)(frow + 32 + quad*8);
  float psum[4] = {0.f, 0.f, 0.f, 0.f};
  for (int t = wave; t < 170; t += 4){
    const unsigned short* kb = K16f + t*1024 + lr*32 + quad*8;
    bf16x8 b0 = *(const bf16x8*)(kb);
    bf16x8 b1 = *(const bf16x8*)(kb + 512);
    f32x4 sv = {};
    sv = __builtin_amdgcn_mfma_f32_16x16x32_bf16(af0, b0, sv, 0, 0, 0);
    sv = __builtin_amdgcn_mfma_f32_16x16x32_bf16(af1, b1, sv, 0, 0, 0);
    if (quad < 2){                       // D rows 0..7 = real P rows
      int col = t*16 + lr;
      int wsh = col >> 5, bit = col & 31;
      #pragma unroll
      for (int e = 0; e < 4; e++){
        int r = quad*4 + e;
        float p = 0.f;
        if ((mrow[r*MWPR + wsh] >> bit) & 1u) p = __expf(fabsf(sv[e]));
        psum[e] += p;
        pbuf[r*PSTR + col] = f2bf(p);
      }
    }
  }
  #pragma unroll
  for (int e = 0; e < 4; e++){           // sum across the 16 lanes of each quad
    float v = psum[e];
    #pragma unroll
    for (int o = 1; o <= 8; o <<= 1) v += __shfl_xor(v, o, 64);
    if (lr == 0 && quad < 2) swave[wave][quad*4 + e] = v;
  }
  __syncthreads();
  if (tid < 8){
    float sum = swave[0][tid] + swave[1][tid] + swave[2][tid] + swave[3][tid];
    rinv[tid] = (sum > 0.f) ? (1.f/sum) : 0.f;
  }
  __syncthreads();

  const int c0 = wave * 16;
  const int mr = lr & 7;
  f32x4 acc = {};
  for (int kt = 0; kt < 85; kt++){
    bf16x8 af = *(const bf16x8*)&pbuf[mr*PSTR + kt*32 + quad*8];
    bf16x8 bv = *(const bf16x8*)&VTf[kt*2048 + (c0 + lr)*32 + quad*8];
    acc = __builtin_amdgcn_mfma_f32_16x16x32_bf16(af, bv, acc, 0, 0, 0);
  }
  if (quad < 2){
    #pragma unroll
    for (int e = 0; e < 4; e++){
      int r = quad*4 + e;
      int i = i0 + r;
      if (i < NV) Hout[(size_t)i*64 + c0 + lr] = acc[e] * rinv[r];
    }
  }
}

extern "C" void kernel_launch(void* const* d_in, const int* in_sizes, int n_in,
                              void* d_out, int out_size, void* d_ws, size_t ws_size,
                              hipStream_t stream){
  (void)in_sizes; (void)n_in; (void)out_size; (void)ws_size;
  const float* X  = (const float*)d_in[0];
  const int*   A  = (const int*)d_in[1];
  const float* U  = (const float*)d_in[2];
  const float* WK = (const float*)d_in[3];
  const float* WQ = (const float*)d_in[4];
  const float* WV = (const float*)d_in[5];
  const float* lm = (const float*)d_in[6];

  char* ws = (char*)d_ws;
  size_t off = 0;
  auto alloc = [&](size_t bytes){ size_t o = off; off = (off + bytes + 255) & ~(size_t)255; return o; };
  float*          part = (float*)(ws + alloc(15*SLAB*4));                      // 10.57 MB
  unsigned short* Ubf  = (unsigned short*)(ws + alloc((size_t)UDIM*UDIM*2));   // 15.15 MB
  unsigned short* Xbf  = (unsigned short*)(ws + alloc((size_t)UDIM*XCOLS*2));  // 8.10 MB
  unsigned short* Wbf  = (unsigned short*)(ws + alloc((size_t)192*XCOLS*2));   // 0.57 MB
  unsigned short* K16f = (unsigned short*)(ws + alloc((size_t)170*1024*2));
  unsigned short* QT16 = (unsigned short*)(ws + alloc((size_t)64*BSTR*2));
  unsigned short* G2T  = (unsigned short*)(ws + alloc((size_t)64*BSTR*2));
  unsigned short* VTf  = (unsigned short*)(ws + alloc((size_t)85*2048*2));
  unsigned short* F16  = (unsigned short*)(ws + alloc((size_t)2720*64*2));
  unsigned int*   Abits= (unsigned int*)(ws + alloc((size_t)NV*MWPR*4));       // 0.95 MB
  // total ~35.4 MB

  convert_all<<<dim3(8404), 256, 0, stream>>>(X, WK, WQ, WV, U, A, Xbf, Wbf, Ubf, Abits);
  proj<<<dim3(43, 4, 3), 256, 0, stream>>>(Xbf, Wbf, part);
  reduce_proj<<<dim3(688, 3), 256, 0, stream>>>(part, K16f, QT16, VTf);
  gemmG<<<dim3(43, 15), 256, 0, stream>>>(Ubf, QT16, part);
  reduce_g<<<dim3(688), 256, 0, stream>>>(part, lm, G2T);
  gemmF<<<dim3(43, 15), 256, 0, stream>>>(Ubf, G2T, part);
  reduce_f<<<dim3(680), 256, 0, stream>>>(part, F16);
  fused_attn<<<dim3((NV + 7)/8), 256, 0, stream>>>(F16, K16f, Abits, VTf, (float*)d_out);
}

// Round 10
// 196.685 us; speedup vs baseline: 1.3016x; 1.0059x over previous
//
#include <hip/hip_runtime.h>

#define NV 2708
#define INC 1433
#define XCOLS 1472        // padded X/W cols (23*64)
#define UDIM 2752         // padded U dims (43*64)
#define PSTR 2720
#define BSTR 2752
#define SLAB ((size_t)(2752*64))   // fp32 partial slab
#define MWPR 88
#define NSP 8             // proj split-K chunks
#define NSU 22            // gemmG/gemmF split-K chunks (2752 = 21*128 + 64)

typedef __attribute__((ext_vector_type(8))) short bf16x8;
typedef __attribute__((ext_vector_type(4))) float f32x4;
typedef __attribute__((ext_vector_type(4))) unsigned short u16x4;

__device__ __forceinline__ unsigned short f2bf(float f){
  union { float f; unsigned int i; } v; v.f = f;
  return (unsigned short)((v.i + 0x7fffu + ((v.i >> 16) & 1u)) >> 16);  // RNE
}

// ====== convert_all: one-row blocks, short per-wave chains ==================
__global__ __launch_bounds__(256) void convert_all(
    const float* __restrict__ X, const float* __restrict__ WK,
    const float* __restrict__ WQ, const float* __restrict__ WV,
    const float* __restrict__ U, const int* __restrict__ A,
    unsigned short* __restrict__ Xbf, unsigned short* __restrict__ Wbf,
    unsigned short* __restrict__ Ubf, unsigned int* __restrict__ Abits)
{
  const int bx = blockIdx.x;
  const int tid = threadIdx.x;
  if (bx < 2752){                      // U row (16B-aligned: float4)
    const int row = bx;
    unsigned short* dst = Ubf + (size_t)row*UDIM;
    if (row < NV){
      const float* src = U + (size_t)row*NV;
      for (int c4 = tid; c4 < 688; c4 += 256){
        float4 v = make_float4(0.f,0.f,0.f,0.f);
        if (c4 < 677) v = *(const float4*)(src + c4*4);
        u16x4 h = { f2bf(v.x), f2bf(v.y), f2bf(v.z), f2bf(v.w) };
        *(u16x4*)(dst + c4*4) = h;
      }
    } else {
      u16x4 zz = {0,0,0,0};
      for (int c4 = tid; c4 < 688; c4 += 256) *(u16x4*)(dst + c4*4) = zz;
    }
  } else if (bx < 5504){               // X row (4B-aligned: scalar)
    const int row = bx - 2752;
    unsigned short* dst = Xbf + (size_t)row*XCOLS;
    if (row < NV){
      const float* src = X + (size_t)row*INC;
      for (int c = tid; c < XCOLS; c += 256)
        dst[c] = (c < INC) ? f2bf(src[c]) : (unsigned short)0;
    } else {
      for (int c = tid; c < XCOLS; c += 256) dst[c] = 0;
    }
  } else if (bx < 5696){               // W row (192 rows)
    const int row = bx - 5504;
    const float* s = (row < 64) ? WK : (row < 128) ? WQ : WV;
    const float* src = s + (size_t)(row & 63)*INC;
    unsigned short* dst = Wbf + (size_t)row*XCOLS;
    for (int c = tid; c < XCOLS; c += 256)
      dst[c] = (c < INC) ? f2bf(src[c]) : (unsigned short)0;
  } else {                             // A row -> bitmask
    const int i = bx - 5696;
    const int lane = tid & 63, wave = tid >> 6;
    const int* arow = A + (size_t)i*NV;
    unsigned int* drow = Abits + (size_t)i*MWPR;
    if (tid < 2) drow[86 + tid] = 0u;
    for (int g = wave; g < 43; g += 4){
      int j = g*64 + lane;
      int a = (j < NV) ? arow[j] : 0;
      unsigned long long m = __ballot(a != 0);
      if (lane == 0){
        drow[2*g]     = (unsigned int)m;
        drow[2*g + 1] = (unsigned int)(m >> 32);
      }
    }
  }
}

// =============== proj: partials of {K,Q,V} = Xbf @ Wbf^T. grid (43,8,3) =====
__global__ __launch_bounds__(256) void proj(
    const unsigned short* __restrict__ Xbf, const unsigned short* __restrict__ Wbf,
    float* __restrict__ part)
{
  __shared__ __align__(16) unsigned short At[64*72];
  __shared__ __align__(16) unsigned short Bt[64*72];
  const int tid = threadIdx.x;
  const int lane = tid & 63, wave = tid >> 6, quad = lane >> 4, lr = lane & 15;
  const int m0 = blockIdx.x * 64;
  const int s  = blockIdx.y, z = blockIdx.z;
  const int kbeg = s * 192, kend = min(kbeg + 192, XCOLS);  // last chunk 128
  const int wm = (wave & 1) * 32, wn = (wave >> 1) * 32;
  const unsigned short* Wz = Wbf + (size_t)z*64*XCOLS;
  const int srow = wave*8 + (lane >> 3), seg = lane & 7;
  f32x4 acc[2][2] = {};

  for (int k0 = kbeg; k0 < kend; k0 += 64){
    #pragma unroll
    for (int e = 0; e < 2; e++){
      int row = e*32 + srow;
      bf16x8 xa = *(const bf16x8*)(Xbf + (size_t)(m0+row)*XCOLS + k0 + seg*8);
      bf16x8 wb = *(const bf16x8*)(Wz  + (size_t)row*XCOLS      + k0 + seg*8);
      *(bf16x8*)&At[row*72 + seg*8] = xa;
      *(bf16x8*)&Bt[row*72 + seg*8] = wb;
    }
    __syncthreads();
    #pragma unroll
    for (int ks = 0; ks < 2; ks++){
      bf16x8 af[2], bv[2];
      #pragma unroll
      for (int t = 0; t < 2; t++){
        af[t] = *(const bf16x8*)&At[(wm + t*16 + lr)*72 + ks*32 + quad*8];
        bv[t] = *(const bf16x8*)&Bt[(wn + t*16 + lr)*72 + ks*32 + quad*8];
      }
      #pragma unroll
      for (int tm = 0; tm < 2; tm++)
        #pragma unroll
        for (int tn = 0; tn < 2; tn++)
          acc[tm][tn] = __builtin_amdgcn_mfma_f32_16x16x32_bf16(af[tm], bv[tn], acc[tm][tn], 0, 0, 0);
    }
    __syncthreads();
  }
  float* dst = part + (size_t)(z*NSP + s) * SLAB;
  #pragma unroll
  for (int tm = 0; tm < 2; tm++)
    #pragma unroll
    for (int tn = 0; tn < 2; tn++)
      #pragma unroll
      for (int e = 0; e < 4; e++)
        dst[(size_t)(m0 + wm + tm*16 + quad*4 + e)*64 + wn + tn*16 + lr] = acc[tm][tn][e];
}

// K16f frag-linear ; QT16 [c][m] ; VTf frag-linear. grid (688, 3).
__global__ __launch_bounds__(256) void reduce_proj(
    const float* __restrict__ part, unsigned short* __restrict__ K16f,
    unsigned short* __restrict__ QT16, unsigned short* __restrict__ VTf)
{
  int idx = blockIdx.x*256 + threadIdx.x;       // < 2752*64
  int z = blockIdx.y;
  int m = idx >> 6, c = idx & 63;
  const float* base = part + (size_t)z*NSP*SLAB + idx;
  float v = 0.f;
  #pragma unroll
  for (int s = 0; s < NSP; s++) v += base[s*SLAB];
  unsigned short h = (m < NV) ? f2bf(v) : (unsigned short)0;
  if (z == 0){
    if (m < 2720) K16f[((m>>4)*2 + (c>>5))*512 + (m&15)*32 + (c&31)] = h;
  } else if (z == 1){
    QT16[(size_t)c*BSTR + m] = h;
  } else {
    if (m < 2720) VTf[(m>>5)*2048 + c*32 + (m&31)] = h;
  }
}

// =============== gemmG: partials of G = Ubf^T @ Q. grid (43,22) =============
__global__ __launch_bounds__(256) void gemmG(
    const unsigned short* __restrict__ Ubf, const unsigned short* __restrict__ QT,
    float* __restrict__ part)
{
  __shared__ __align__(16) unsigned short At[64*72];
  __shared__ __align__(16) unsigned short Bt[64*72];
  const int tid = threadIdx.x;
  const int lane = tid & 63, wave = tid >> 6, quad = lane >> 4, lr = lane & 15;
  const int m0 = blockIdx.x * 64;
  const int s  = blockIdx.y;
  const int kbeg = s * 128, kend = min(kbeg + 128, UDIM);   // last chunk 64
  const int wm = (wave & 1) * 32, wn = (wave >> 1) * 32;
  const int bc = tid >> 2, bseg = tid & 3;
  const int ml = (lane & 15)*4, koff = wave*16 + (lane >> 4);
  f32x4 acc[2][2] = {};

  for (int k0 = kbeg; k0 < kend; k0 += 64){
    #pragma unroll
    for (int e = 0; e < 4; e++){
      int kl = koff + e*4;
      u16x4 v = *(const u16x4*)(Ubf + (size_t)(k0+kl)*UDIM + m0 + ml);
      At[(ml+0)*72 + kl] = v[0];
      At[(ml+1)*72 + kl] = v[1];
      At[(ml+2)*72 + kl] = v[2];
      At[(ml+3)*72 + kl] = v[3];
    }
    {
      const unsigned short* q = QT + (size_t)bc*BSTR + k0 + bseg*16;
      *(bf16x8*)&Bt[bc*72 + bseg*16]     = *(const bf16x8*)(q);
      *(bf16x8*)&Bt[bc*72 + bseg*16 + 8] = *(const bf16x8*)(q + 8);
    }
    __syncthreads();
    #pragma unroll
    for (int ks = 0; ks < 2; ks++){
      bf16x8 af[2], bv[2];
      #pragma unroll
      for (int t = 0; t < 2; t++){
        af[t] = *(const bf16x8*)&At[(wm + t*16 + lr)*72 + ks*32 + quad*8];
        bv[t] = *(const bf16x8*)&Bt[(wn + t*16 + lr)*72 + ks*32 + quad*8];
      }
      #pragma unroll
      for (int tm = 0; tm < 2; tm++)
        #pragma unroll
        for (int tn = 0; tn < 2; tn++)
          acc[tm][tn] = __builtin_amdgcn_mfma_f32_16x16x32_bf16(af[tm], bv[tn], acc[tm][tn], 0, 0, 0);
    }
    __syncthreads();
  }
  float* dst = part + (size_t)s * SLAB;
  #pragma unroll
  for (int tm = 0; tm < 2; tm++)
    #pragma unroll
    for (int tn = 0; tn < 2; tn++)
      #pragma unroll
      for (int e = 0; e < 4; e++)
        dst[(size_t)(m0 + wm + tm*16 + quad*4 + e)*64 + wn + tn*16 + lr] = acc[tm][tn][e];
}

// G2T16[c][m] = bf16(G[m][c] * lmbd[m]/64), zero pads. grid 688.
__global__ __launch_bounds__(256) void reduce_g(
    const float* __restrict__ part, const float* __restrict__ lm,
    unsigned short* __restrict__ G2T)
{
  int idx = blockIdx.x*256 + threadIdx.x;
  int m = idx >> 6, c = idx & 63;
  const float* base = part + idx;
  float v = 0.f;
  #pragma unroll
  for (int s = 0; s < NSU; s++) v += base[s*SLAB];
  unsigned short h = 0;
  if (m < NV) h = f2bf(v * lm[m] * (1.0f/64.0f));
  G2T[(size_t)c*BSTR + m] = h;
}

// =============== gemmF: partials of F = Ubf @ G2. grid (43,22) ==============
__global__ __launch_bounds__(256) void gemmF(
    const unsigned short* __restrict__ Ubf, const unsigned short* __restrict__ G2T,
    float* __restrict__ part)
{
  __shared__ __align__(16) unsigned short At[64*72];
  __shared__ __align__(16) unsigned short Bt[64*72];
  const int tid = threadIdx.x;
  const int lane = tid & 63, wave = tid >> 6, quad = lane >> 4, lr = lane & 15;
  const int m0 = blockIdx.x * 64;
  const int s  = blockIdx.y;
  const int kbeg = s * 128, kend = min(kbeg + 128, UDIM);
  const int wm = (wave & 1) * 32, wn = (wave >> 1) * 32;
  const int bc = tid >> 2, bseg = tid & 3;
  const int srow = wave*8 + (lane >> 3), seg = lane & 7;
  f32x4 acc[2][2] = {};

  for (int k0 = kbeg; k0 < kend; k0 += 64){
    #pragma unroll
    for (int e = 0; e < 2; e++){
      int row = e*32 + srow;
      bf16x8 ua = *(const bf16x8*)(Ubf + (size_t)(m0+row)*UDIM + k0 + seg*8);
      *(bf16x8*)&At[row*72 + seg*8] = ua;
    }
    {
      const unsigned short* g = G2T + (size_t)bc*BSTR + k0 + bseg*16;
      *(bf16x8*)&Bt[bc*72 + bseg*16]     = *(const bf16x8*)(g);
      *(bf16x8*)&Bt[bc*72 + bseg*16 + 8] = *(const bf16x8*)(g + 8);
    }
    __syncthreads();
    #pragma unroll
    for (int ks = 0; ks < 2; ks++){
      bf16x8 af[2], bv[2];
      #pragma unroll
      for (int t = 0; t < 2; t++){
        af[t] = *(const bf16x8*)&At[(wm + t*16 + lr)*72 + ks*32 + quad*8];
        bv[t] = *(const bf16x8*)&Bt[(wn + t*16 + lr)*72 + ks*32 + quad*8];
      }
      #pragma unroll
      for (int tm = 0; tm < 2; tm++)
        #pragma unroll
        for (int tn = 0; tn < 2; tn++)
          acc[tm][tn] = __builtin_amdgcn_mfma_f32_16x16x32_bf16(af[tm], bv[tn], acc[tm][tn], 0, 0, 0);
    }
    __syncthreads();
  }
  float* dst = part + (size_t)s * SLAB;
  #pragma unroll
  for (int tm = 0; tm < 2; tm++)
    #pragma unroll
    for (int tn = 0; tn < 2; tn++)
      #pragma unroll
      for (int e = 0; e < 4; e++)
        dst[(size_t)(m0 + wm + tm*16 + quad*4 + e)*64 + wn + tn*16 + lr] = acc[tm][tn][e];
}

// ====== fused: reduce-F + |F K^T| -> masked exp + row-sum -> P V ============
// 8 rows/block, 339 blocks. F staged from the 22 part slabs via LDS (folds
// reduce_f). Phase A/C software-pipelined (prefetch K16f / VTf across MFMA).
__global__ __launch_bounds__(256) void fused_attn(
    const float* __restrict__ partF, const unsigned short* __restrict__ K16f,
    const unsigned int* __restrict__ Abits, const unsigned short* __restrict__ VTf,
    float* __restrict__ Hout)
{
  __shared__ __align__(16) unsigned short pbuf[8*PSTR];   // 43.5 KB
  __shared__ __align__(16) unsigned short fbuf[8*64];
  __shared__ unsigned int mrow[8*MWPR];
  __shared__ float swave[4][8];
  __shared__ float rinv[8];
  const int tid  = threadIdx.x;
  const int lane = tid & 63, wave = tid >> 6;
  const int quad = lane >> 4, lr = lane & 15;
  const int i0 = blockIdx.x * 8;

  // stage F rows (sum 22 slabs; rows >= NV are zero in part)
  #pragma unroll
  for (int h = 0; h < 2; h++){
    int idx = h*256 + tid;              // < 512
    const float* base = partF + (size_t)(i0 + (idx >> 6))*64 + (idx & 63);
    float v = 0.f;
    #pragma unroll
    for (int s = 0; s < NSU; s++) v += base[s*SLAB];
    fbuf[idx] = f2bf(v);
  }
  for (int idx = tid; idx < 8*MWPR; idx += 256){
    int r = idx / MWPR;
    unsigned int v = 0;
    if (i0 + r < NV) v = Abits[(size_t)(i0 + r)*MWPR + (idx - r*MWPR)];
    mrow[idx] = v;
  }
  __syncthreads();

  const bf16x8 af0 = *(const bf16x8*)&fbuf[(lr & 7)*64 + quad*8];
  const bf16x8 af1 = *(const bf16x8*)&fbuf[(lr & 7)*64 + 32 + quad*8];
  float psum[4] = {0.f, 0.f, 0.f, 0.f};
  {
    int t = wave;
    const unsigned short* kb = K16f + t*1024 + lr*32 + quad*8;
    bf16x8 b0 = *(const bf16x8*)(kb);
    bf16x8 b1 = *(const bf16x8*)(kb + 512);
    while (t < 170){
      int tn = t + 4;
      bf16x8 n0 = b0, n1 = b1;
      if (tn < 170){
        const unsigned short* nb = K16f + tn*1024 + lr*32 + quad*8;
        n0 = *(const bf16x8*)(nb);
        n1 = *(const bf16x8*)(nb + 512);
      }
      f32x4 sv = {};
      sv = __builtin_amdgcn_mfma_f32_16x16x32_bf16(af0, b0, sv, 0, 0, 0);
      sv = __builtin_amdgcn_mfma_f32_16x16x32_bf16(af1, b1, sv, 0, 0, 0);
      if (quad < 2){
        int col = t*16 + lr;
        int wsh = col >> 5, bit = col & 31;
        #pragma unroll
        for (int e = 0; e < 4; e++){
          int r = quad*4 + e;
          float p = 0.f;
          if ((mrow[r*MWPR + wsh] >> bit) & 1u) p = __expf(fabsf(sv[e]));
          psum[e] += p;
          pbuf[r*PSTR + col] = f2bf(p);
        }
      }
      b0 = n0; b1 = n1; t = tn;
    }
  }
  #pragma unroll
  for (int e = 0; e < 4; e++){
    float v = psum[e];
    #pragma unroll
    for (int o = 1; o <= 8; o <<= 1) v += __shfl_xor(v, o, 64);
    if (lr == 0 && quad < 2) swave[wave][quad*4 + e] = v;
  }
  __syncthreads();
  if (tid < 8){
    float sum = swave[0][tid] + swave[1][tid] + swave[2][tid] + swave[3][tid];
    rinv[tid] = (sum > 0.f) ? (1.f/sum) : 0.f;
  }
  __syncthreads();

  const int c0 = wave * 16;
  const int mr = lr & 7;
  f32x4 acc = {};
  {
    bf16x8 bv = *(const bf16x8*)&VTf[(c0 + lr)*32 + quad*8];
    for (int kt = 0; kt < 85; kt++){
      bf16x8 bn = bv;
      if (kt + 1 < 85) bn = *(const bf16x8*)&VTf[(kt+1)*2048 + (c0 + lr)*32 + quad*8];
      bf16x8 af = *(const bf16x8*)&pbuf[mr*PSTR + kt*32 + quad*8];
      acc = __builtin_amdgcn_mfma_f32_16x16x32_bf16(af, bv, acc, 0, 0, 0);
      bv = bn;
    }
  }
  if (quad < 2){
    #pragma unroll
    for (int e = 0; e < 4; e++){
      int r = quad*4 + e;
      int i = i0 + r;
      if (i < NV) Hout[(size_t)i*64 + c0 + lr] = acc[e] * rinv[r];
    }
  }
}

extern "C" void kernel_launch(void* const* d_in, const int* in_sizes, int n_in,
                              void* d_out, int out_size, void* d_ws, size_t ws_size,
                              hipStream_t stream){
  (void)in_sizes; (void)n_in; (void)out_size; (void)ws_size;
  const float* X  = (const float*)d_in[0];
  const int*   A  = (const int*)d_in[1];
  const float* U  = (const float*)d_in[2];
  const float* WK = (const float*)d_in[3];
  const float* WQ = (const float*)d_in[4];
  const float* WV = (const float*)d_in[5];
  const float* lm = (const float*)d_in[6];

  char* ws = (char*)d_ws;
  size_t off = 0;
  auto alloc = [&](size_t bytes){ size_t o = off; off = (off + bytes + 255) & ~(size_t)255; return o; };
  float*          part = (float*)(ws + alloc(24*SLAB*4));                      // 16.9 MB
  unsigned short* Ubf  = (unsigned short*)(ws + alloc((size_t)UDIM*UDIM*2));   // 15.15 MB
  unsigned short* Xbf  = (unsigned short*)(ws + alloc((size_t)UDIM*XCOLS*2));  // 8.10 MB
  unsigned short* Wbf  = (unsigned short*)(ws + alloc((size_t)192*XCOLS*2));
  unsigned short* K16f = (unsigned short*)(ws + alloc((size_t)170*1024*2));
  unsigned short* QT16 = (unsigned short*)(ws + alloc((size_t)64*BSTR*2));
  unsigned short* G2T  = (unsigned short*)(ws + alloc((size_t)64*BSTR*2));
  unsigned short* VTf  = (unsigned short*)(ws + alloc((size_t)85*2048*2));
  unsigned int*   Abits= (unsigned int*)(ws + alloc((size_t)NV*MWPR*4));
  // total ~43 MB (ws_size = 256 MB per round-9 profile)

  convert_all<<<dim3(8404), 256, 0, stream>>>(X, WK, WQ, WV, U, A, Xbf, Wbf, Ubf, Abits);
  proj<<<dim3(43, NSP, 3), 256, 0, stream>>>(Xbf, Wbf, part);
  reduce_proj<<<dim3(688, 3), 256, 0, stream>>>(part, K16f, QT16, VTf);
  gemmG<<<dim3(43, NSU), 256, 0, stream>>>(Ubf, QT16, part);
  reduce_g<<<dim3(688), 256, 0, stream>>>(part, lm, G2T);
  gemmF<<<dim3(43, NSU), 256, 0, stream>>>(Ubf, G2T, part);
  fused_attn<<<dim3((NV + 7)/8), 256, 0, stream>>>(part, K16f, Abits, VTf, (float*)d_out);
}